// Round 4
// baseline (377.940 us; speedup 1.0000x reference)
//
#include <hip/hip_runtime.h>
#include <hip/hip_fp16.h>

// GAT layer: N=50000 nodes, S=2 slots, D=128, E=800000 edges.
// out[n] = (sum_e{dst=n} w_e * h[src_e]) / (sum w_e)  for deg>0, else h[n]
// w_e = exp(leaky_relu(ps[src]+pd[dst]))  (segment-max dropped: a~N(0,1),
// exp range [7e-3,250], fp32-safe — validated R3, absmax 0.0039)
//
// R4 changes: fp16 gather copy of h (halves bytes), 2-edge/wave-iter agg
// (halves requests), self-normalizing agg (edge2: 1 atomic), 5 graph nodes.

#define SLOPE 0.98f
#define FEAT 256          // S*D floats per node
#define FEAT4 64          // float4 per node

// ---- fused: [blocks < nPB] proj + fp16 compress ; [rest] degree histogram ----
__global__ __launch_bounds__(256) void fused1_kernel(
    const float* __restrict__ h, const float* __restrict__ watt,
    const int* __restrict__ dst,
    float* __restrict__ ps, float* __restrict__ pd,
    uint2* __restrict__ hh, int* __restrict__ deg,
    int n_nodes, int ne, int n_proj_blocks, int do_fp16) {
    if ((int)blockIdx.x < n_proj_blocks) {
        int lane = threadIdx.x & 63;
        int node = blockIdx.x * 4 + (threadIdx.x >> 6);
        if (node >= n_nodes) return;                       // wave-uniform
        const float4* hv = (const float4*)h;
        float4 f = hv[(size_t)node * FEAT4 + lane];        // floats 4l..4l+3
        if (do_fp16) {
            __half2 lo = __floats2half2_rn(f.x, f.y);
            __half2 hi = __floats2half2_rn(f.z, f.w);
            uint2 pk;
            pk.x = *(unsigned*)&lo;
            pk.y = *(unsigned*)&hi;
            hh[(size_t)node * FEAT4 + lane] = pk;          // same linear layout
        }
        float p_s = 0.f, p_d = 0.f;
        if (lane < 32) {                                   // slot0 = floats 0..127
            float4 w1 = ((const float4*)watt)[lane];       // watt[4l..4l+3]
            float4 w2 = ((const float4*)watt)[32 + lane];  // watt[128+4l..]
            p_s = f.x * w1.x + f.y * w1.y + f.z * w1.z + f.w * w1.w;
            p_d = f.x * w2.x + f.y * w2.y + f.z * w2.z + f.w * w2.w;
        }
        #pragma unroll
        for (int off = 32; off; off >>= 1) {
            p_s += __shfl_xor(p_s, off, 64);
            p_d += __shfl_xor(p_d, off, 64);
        }
        if (lane == 0) { ps[node] = p_s; pd[node] = p_d; }
    } else {
        int e = ((int)blockIdx.x - n_proj_blocks) * 256 + threadIdx.x;
        if (e < ne) atomicAdd(&deg[dst[e]], 1);
    }
}

// ---- single-block exclusive scan: deg -> offs (+copy offs_mut, offs[n]=E) ----
__global__ __launch_bounds__(1024) void scan_kernel(
    const int* __restrict__ deg, int* __restrict__ offs,
    int* __restrict__ offs_mut, int n) {
    __shared__ int wsum[16];
    int t = threadIdx.x;
    int ch = (n + 1023) >> 10;                 // items per thread
    int base = t * ch;
    int tsum = 0;
    for (int j = 0; j < ch; ++j) { int i = base + j; if (i < n) tsum += deg[i]; }
    int lane = t & 63, wid = t >> 6;
    int incl = tsum;
    #pragma unroll
    for (int off = 1; off < 64; off <<= 1) {
        int u = __shfl_up(incl, off, 64);
        if (lane >= off) incl += u;
    }
    if (lane == 63) wsum[wid] = incl;
    __syncthreads();
    if (t < 16) {
        int v = wsum[t];
        #pragma unroll
        for (int off = 1; off < 16; off <<= 1) {
            int u = __shfl_up(v, off, 64);
            if (t >= off) v += u;
        }
        wsum[t] = v;
    }
    __syncthreads();
    int run = (wid ? wsum[wid - 1] : 0) + incl - tsum;   // exclusive prefix
    for (int j = 0; j < ch; ++j) {
        int i = base + j;
        if (i < n) { offs[i] = run; offs_mut[i] = run; run += deg[i]; }
    }
    if (t == 1023) offs[n] = run;              // thread 1023's chunk covers end
}

// ---- edge pass: logit, exp, CSR placement (single atomic) ----
__global__ __launch_bounds__(256) void edge2_kernel(
    const int* __restrict__ src, const int* __restrict__ dst,
    const float* __restrict__ ps, const float* __restrict__ pd,
    int* __restrict__ offs_mut,
    int* __restrict__ esrc, float* __restrict__ ew, int ne) {
    int e = blockIdx.x * 256 + threadIdx.x;
    if (e >= ne) return;
    int sn = src[e], dn = dst[e];
    float v = ps[sn] + pd[dn];
    v = (v >= 0.0f) ? v : SLOPE * v;
    float w = __expf(v);
    int p = atomicAdd(&offs_mut[dn], 1);
    esrc[p] = sn;
    ew[p] = w;
}

__device__ inline void accum8(float4& a, float4& b, uint4 p, float w) {
    __half2 h0 = *(__half2*)&p.x, h1 = *(__half2*)&p.y;
    __half2 h2 = *(__half2*)&p.z, h3 = *(__half2*)&p.w;
    float2 f0 = __half22float2(h0), f1 = __half22float2(h1);
    float2 f2 = __half22float2(h2), f3 = __half22float2(h3);
    a.x += w * f0.x; a.y += w * f0.y; a.z += w * f1.x; a.w += w * f1.y;
    b.x += w * f2.x; b.y += w * f2.y; b.z += w * f3.x; b.w += w * f3.y;
}

// ---- aggregation (fp16 source): wave/node, 2 edges per iter (32 lanes x 16B
// cover one 512B slab), self-normalizing ----
__global__ __launch_bounds__(256) void agg16_kernel(
    const float* __restrict__ h, const uint4* __restrict__ hh,
    const int* __restrict__ offs, const int* __restrict__ esrc,
    const float* __restrict__ ew, float* __restrict__ out, int n_nodes) {
    int lane = threadIdx.x & 63;
    int node = blockIdx.x * 4 + (threadIdx.x >> 6);
    if (node >= n_nodes) return;
    int beg = offs[node], end = offs[node + 1];
    if (beg == end) {                                    // keep old features
        const float4* hv = (const float4*)h;
        ((float4*)out)[(size_t)node * FEAT4 + lane] = hv[(size_t)node * FEAT4 + lane];
        return;
    }
    int  hl  = lane & 31;
    bool loA = lane < 32;
    float4 a = {0, 0, 0, 0}, b = {0, 0, 0, 0};           // floats 8*hl .. 8*hl+7
    float ssum = 0.f;
    for (int base = beg; base < end; base += 64) {
        int k = base + lane;
        int sj = 0; float wj = 0.f;
        if (k < end) { sj = esrc[k]; wj = ew[k]; }
        ssum += wj;
        int cnt = min(64, end - base);
        int t = 0;
        for (; t + 4 <= cnt; t += 4) {                   // 4 edges, 2 loads/lane
            int   s0 = __shfl(sj, t, 64),     s1 = __shfl(sj, t + 1, 64);
            int   s2 = __shfl(sj, t + 2, 64), s3 = __shfl(sj, t + 3, 64);
            float w0 = __shfl(wj, t, 64),     w1 = __shfl(wj, t + 1, 64);
            float w2 = __shfl(wj, t + 2, 64), w3 = __shfl(wj, t + 3, 64);
            int   iA = loA ? s0 : s1,  iB = loA ? s2 : s3;
            float wA = loA ? w0 : w1,  wB = loA ? w2 : w3;
            uint4 pA = hh[(size_t)iA * 32 + hl];         // independent
            uint4 pB = hh[(size_t)iB * 32 + hl];         // gathers
            accum8(a, b, pA, wA);
            accum8(a, b, pB, wB);
        }
        for (; t < cnt; t += 2) {                        // 1-3 remaining edges
            int  s0 = __shfl(sj, t, 64);
            bool hasB = (t + 1) < cnt;
            int   s1 = hasB ? __shfl(sj, t + 1, 64) : s0;
            float w0 = __shfl(wj, t, 64);
            float w1 = hasB ? __shfl(wj, t + 1, 64) : 0.f;
            int   iA = loA ? s0 : s1;
            float wA = loA ? w0 : w1;
            uint4 pA = hh[(size_t)iA * 32 + hl];
            accum8(a, b, pA, wA);
        }
    }
    // combine the two half-wave partials (lane m <-> lane m+32 hold same floats)
    a.x += __shfl_xor(a.x, 32, 64); a.y += __shfl_xor(a.y, 32, 64);
    a.z += __shfl_xor(a.z, 32, 64); a.w += __shfl_xor(a.w, 32, 64);
    b.x += __shfl_xor(b.x, 32, 64); b.y += __shfl_xor(b.y, 32, 64);
    b.z += __shfl_xor(b.z, 32, 64); b.w += __shfl_xor(b.w, 32, 64);
    #pragma unroll
    for (int off = 32; off; off >>= 1) ssum += __shfl_xor(ssum, off, 64);
    if (loA) {
        float inv = 1.f / ssum;
        float4 o0 = {a.x * inv, a.y * inv, a.z * inv, a.w * inv};
        float4 o1 = {b.x * inv, b.y * inv, b.z * inv, b.w * inv};
        float4* op = (float4*)(out + (size_t)node * FEAT + hl * 8);
        op[0] = o0; op[1] = o1;
    }
}

// ---- fallback aggregation (fp32 source), self-normalizing ----
__global__ __launch_bounds__(256) void agg32_kernel(
    const float* __restrict__ h, const int* __restrict__ offs,
    const int* __restrict__ esrc, const float* __restrict__ ew,
    float* __restrict__ out, int n_nodes) {
    int lane = threadIdx.x & 63;
    int node = blockIdx.x * 4 + (threadIdx.x >> 6);
    if (node >= n_nodes) return;
    int beg = offs[node], end = offs[node + 1];
    const float4* __restrict__ hv = (const float4*)h;
    float4 acc = {0, 0, 0, 0};
    if (beg == end) {
        acc = hv[(size_t)node * FEAT4 + lane];
    } else {
        float ssum = 0.f;
        for (int base = beg; base < end; base += 64) {
            int k = base + lane;
            int sj = 0; float wj = 0.f;
            if (k < end) { sj = esrc[k]; wj = ew[k]; }
            ssum += wj;
            int cnt = min(64, end - base);
            for (int j = 0; j < cnt; ++j) {
                int   srcn = __shfl(sj, j, 64);
                float al   = __shfl(wj, j, 64);
                float4 hv4 = hv[(size_t)srcn * FEAT4 + lane];
                acc.x += al * hv4.x; acc.y += al * hv4.y;
                acc.z += al * hv4.z; acc.w += al * hv4.w;
            }
        }
        #pragma unroll
        for (int off = 32; off; off >>= 1) ssum += __shfl_xor(ssum, off, 64);
        float inv = 1.f / ssum;
        acc.x *= inv; acc.y *= inv; acc.z *= inv; acc.w *= inv;
    }
    ((float4*)out)[(size_t)node * FEAT4 + lane] = acc;
}

extern "C" void kernel_launch(void* const* d_in, const int* in_sizes, int n_in,
                              void* d_out, int out_size, void* d_ws, size_t ws_size,
                              hipStream_t stream) {
    const float* h    = (const float*)d_in[0];
    const int*   src  = (const int*)d_in[1];
    const int*   dst  = (const int*)d_in[2];
    const float* watt = (const float*)d_in[3];
    float* out = (float*)d_out;

    const int nN = in_sizes[0] / FEAT;   // 50000
    const int nE = in_sizes[1];          // 800000

    char* w = (char*)d_ws;
    size_t off = 0;
    auto take = [&](size_t bytes) -> char* {
        char* p = w + off;
        off = (off + bytes + 255) & ~(size_t)255;
        return p;
    };
    float* ps       = (float*)take((size_t)nN * 4);
    float* pd       = (float*)take((size_t)nN * 4);
    int*   deg      = (int*)take((size_t)nN * 4);
    int*   offs     = (int*)take((size_t)(nN + 1) * 4);
    int*   offs_mut = (int*)take((size_t)nN * 4);
    int*   esrc     = (int*)take((size_t)nE * 4);
    float* ew       = (float*)take((size_t)nE * 4);
    char*  hh       = take((size_t)nN * FEAT * 2);   // 25.6 MB fp16 copy
    int fp16ok = (off <= ws_size) ? 1 : 0;

    hipMemsetAsync(deg, 0, (size_t)nN * 4, stream);

    int nPB = (nN + 3) / 4;          // proj/agg blocks (4 nodes each)
    int nEB = (nE + 255) / 256;      // edge blocks
    fused1_kernel<<<nPB + nEB, 256, 0, stream>>>(h, watt, dst, ps, pd,
                                                 (uint2*)hh, deg, nN, nE, nPB, fp16ok);
    scan_kernel  <<<1, 1024, 0, stream>>>(deg, offs, offs_mut, nN);
    edge2_kernel <<<nEB, 256, 0, stream>>>(src, dst, ps, pd, offs_mut, esrc, ew, nE);
    if (fp16ok)
        agg16_kernel<<<nPB, 256, 0, stream>>>(h, (const uint4*)hh, offs, esrc, ew, out, nN);
    else
        agg32_kernel<<<nPB, 256, 0, stream>>>(h, offs, esrc, ew, out, nN);
}

// Round 5
// 263.445 us; speedup vs baseline: 1.4346x; 1.4346x over previous
//
#include <hip/hip_runtime.h>
#include <hip/hip_fp16.h>

// GAT layer: N=50000 nodes, S=2 slots, D=128, E=800000 edges.
// out[n] = (sum_e{dst=n} w_e * h[src_e]) / (sum w_e)  for deg>0, else h[n]
// w_e = exp(leaky_relu(ps[src]+pd[dst]))  (segment-max dropped: a~N(0,1),
// exp range [7e-3,250], fp32-safe — validated R3/R4)
//
// R5: revert R4's single-block scan (127us, one CU, latency-bound) to the
// R3 hierarchical 3-kernel scan. fp16 gather copy + 2-edge agg kept from R4.

#define SLOPE 0.98f
#define FEAT 256          // S*D floats per node
#define FEAT4 64          // float4 per node

// ---- fused: [blocks < nPB] proj + fp16 compress ; [rest] degree histogram ----
__global__ __launch_bounds__(256) void fused1_kernel(
    const float* __restrict__ h, const float* __restrict__ watt,
    const int* __restrict__ dst,
    float* __restrict__ ps, float* __restrict__ pd,
    uint2* __restrict__ hh, int* __restrict__ deg,
    int n_nodes, int ne, int n_proj_blocks, int do_fp16) {
    if ((int)blockIdx.x < n_proj_blocks) {
        int lane = threadIdx.x & 63;
        int node = blockIdx.x * 4 + (threadIdx.x >> 6);
        if (node >= n_nodes) return;                       // wave-uniform
        const float4* hv = (const float4*)h;
        float4 f = hv[(size_t)node * FEAT4 + lane];        // floats 4l..4l+3
        if (do_fp16) {
            __half2 lo = __floats2half2_rn(f.x, f.y);
            __half2 hi = __floats2half2_rn(f.z, f.w);
            uint2 pk;
            pk.x = *(unsigned*)&lo;
            pk.y = *(unsigned*)&hi;
            hh[(size_t)node * FEAT4 + lane] = pk;          // same linear layout
        }
        float p_s = 0.f, p_d = 0.f;
        if (lane < 32) {                                   // slot0 = floats 0..127
            float4 w1 = ((const float4*)watt)[lane];       // watt[4l..4l+3]
            float4 w2 = ((const float4*)watt)[32 + lane];  // watt[128+4l..]
            p_s = f.x * w1.x + f.y * w1.y + f.z * w1.z + f.w * w1.w;
            p_d = f.x * w2.x + f.y * w2.y + f.z * w2.z + f.w * w2.w;
        }
        #pragma unroll
        for (int off = 32; off; off >>= 1) {
            p_s += __shfl_xor(p_s, off, 64);
            p_d += __shfl_xor(p_d, off, 64);
        }
        if (lane == 0) { ps[node] = p_s; pd[node] = p_d; }
    } else {
        int e = ((int)blockIdx.x - n_proj_blocks) * 256 + threadIdx.x;
        if (e < ne) atomicAdd(&deg[dst[e]], 1);
    }
}

// ---- hierarchical exclusive scan: deg -> offs (3 small parallel kernels) ----
__global__ __launch_bounds__(1024) void scan1_kernel(
    const int* __restrict__ deg, int* __restrict__ offs,
    int* __restrict__ partial, int n) {
    __shared__ int wsum[16];
    int i = blockIdx.x * 1024 + threadIdx.x;
    int v = (i < n) ? deg[i] : 0;
    int lane = threadIdx.x & 63, wid = threadIdx.x >> 6;
    int incl = v;
    #pragma unroll
    for (int off = 1; off < 64; off <<= 1) {
        int t = __shfl_up(incl, off, 64);
        if (lane >= off) incl += t;
    }
    if (lane == 63) wsum[wid] = incl;
    __syncthreads();
    if (threadIdx.x < 16) {
        int t = wsum[threadIdx.x];
        #pragma unroll
        for (int off = 1; off < 16; off <<= 1) {
            int u = __shfl_up(t, off, 64);
            if ((int)threadIdx.x >= off) t += u;
        }
        wsum[threadIdx.x] = t;
    }
    __syncthreads();
    int wbase = wid ? wsum[wid - 1] : 0;
    if (i < n) offs[i] = wbase + incl - v;        // exclusive within block
    if (threadIdx.x == 1023) partial[blockIdx.x] = wsum[15];
}

__global__ void scan2_kernel(int* __restrict__ partial, int nb) {
    int lane = threadIdx.x;                        // 64 threads, nb<=64
    int v = (lane < nb) ? partial[lane] : 0;
    int incl = v;
    #pragma unroll
    for (int off = 1; off < 64; off <<= 1) {
        int t = __shfl_up(incl, off, 64);
        if (lane >= off) incl += t;
    }
    if (lane < nb) partial[lane] = incl - v;       // exclusive block bases
}

__global__ __launch_bounds__(1024) void scan3_kernel(
    int* __restrict__ offs, int* __restrict__ offs_mut,
    const int* __restrict__ partial, int n, int ne) {
    int i = blockIdx.x * 1024 + threadIdx.x;
    if (i < n) {
        int v = offs[i] + partial[blockIdx.x];
        offs[i] = v;
        offs_mut[i] = v;
    }
    if (i == 0) offs[n] = ne;
}

// ---- edge pass: logit, exp, CSR placement (single atomic) ----
__global__ __launch_bounds__(256) void edge2_kernel(
    const int* __restrict__ src, const int* __restrict__ dst,
    const float* __restrict__ ps, const float* __restrict__ pd,
    int* __restrict__ offs_mut,
    int* __restrict__ esrc, float* __restrict__ ew, int ne) {
    int e = blockIdx.x * 256 + threadIdx.x;
    if (e >= ne) return;
    int sn = src[e], dn = dst[e];
    float v = ps[sn] + pd[dn];
    v = (v >= 0.0f) ? v : SLOPE * v;
    float w = __expf(v);
    int p = atomicAdd(&offs_mut[dn], 1);
    esrc[p] = sn;
    ew[p] = w;
}

__device__ inline void accum8(float4& a, float4& b, uint4 p, float w) {
    __half2 h0 = *(__half2*)&p.x, h1 = *(__half2*)&p.y;
    __half2 h2 = *(__half2*)&p.z, h3 = *(__half2*)&p.w;
    float2 f0 = __half22float2(h0), f1 = __half22float2(h1);
    float2 f2 = __half22float2(h2), f3 = __half22float2(h3);
    a.x += w * f0.x; a.y += w * f0.y; a.z += w * f1.x; a.w += w * f1.y;
    b.x += w * f2.x; b.y += w * f2.y; b.z += w * f3.x; b.w += w * f3.y;
}

// ---- aggregation (fp16 source): wave/node, 2 edges per iter (32 lanes x 16B
// cover one 512B slab), self-normalizing ----
__global__ __launch_bounds__(256) void agg16_kernel(
    const float* __restrict__ h, const uint4* __restrict__ hh,
    const int* __restrict__ offs, const int* __restrict__ esrc,
    const float* __restrict__ ew, float* __restrict__ out, int n_nodes) {
    int lane = threadIdx.x & 63;
    int node = blockIdx.x * 4 + (threadIdx.x >> 6);
    if (node >= n_nodes) return;
    int beg = offs[node], end = offs[node + 1];
    if (beg == end) {                                    // keep old features
        const float4* hv = (const float4*)h;
        ((float4*)out)[(size_t)node * FEAT4 + lane] = hv[(size_t)node * FEAT4 + lane];
        return;
    }
    int  hl  = lane & 31;
    bool loA = lane < 32;
    float4 a = {0, 0, 0, 0}, b = {0, 0, 0, 0};           // floats 8*hl .. 8*hl+7
    float ssum = 0.f;
    for (int base = beg; base < end; base += 64) {
        int k = base + lane;
        int sj = 0; float wj = 0.f;
        if (k < end) { sj = esrc[k]; wj = ew[k]; }
        ssum += wj;
        int cnt = min(64, end - base);
        int t = 0;
        for (; t + 4 <= cnt; t += 4) {                   // 4 edges, 2 loads/lane
            int   s0 = __shfl(sj, t, 64),     s1 = __shfl(sj, t + 1, 64);
            int   s2 = __shfl(sj, t + 2, 64), s3 = __shfl(sj, t + 3, 64);
            float w0 = __shfl(wj, t, 64),     w1 = __shfl(wj, t + 1, 64);
            float w2 = __shfl(wj, t + 2, 64), w3 = __shfl(wj, t + 3, 64);
            int   iA = loA ? s0 : s1,  iB = loA ? s2 : s3;
            float wA = loA ? w0 : w1,  wB = loA ? w2 : w3;
            uint4 pA = hh[(size_t)iA * 32 + hl];         // independent
            uint4 pB = hh[(size_t)iB * 32 + hl];         // gathers
            accum8(a, b, pA, wA);
            accum8(a, b, pB, wB);
        }
        for (; t < cnt; t += 2) {                        // 1-3 remaining edges
            int  s0 = __shfl(sj, t, 64);
            bool hasB = (t + 1) < cnt;
            int   s1 = hasB ? __shfl(sj, t + 1, 64) : s0;
            float w0 = __shfl(wj, t, 64);
            float w1 = hasB ? __shfl(wj, t + 1, 64) : 0.f;
            int   iA = loA ? s0 : s1;
            float wA = loA ? w0 : w1;
            uint4 pA = hh[(size_t)iA * 32 + hl];
            accum8(a, b, pA, wA);
        }
    }
    // combine the two half-wave partials (lane m <-> lane m+32 hold same floats)
    a.x += __shfl_xor(a.x, 32, 64); a.y += __shfl_xor(a.y, 32, 64);
    a.z += __shfl_xor(a.z, 32, 64); a.w += __shfl_xor(a.w, 32, 64);
    b.x += __shfl_xor(b.x, 32, 64); b.y += __shfl_xor(b.y, 32, 64);
    b.z += __shfl_xor(b.z, 32, 64); b.w += __shfl_xor(b.w, 32, 64);
    #pragma unroll
    for (int off = 32; off; off >>= 1) ssum += __shfl_xor(ssum, off, 64);
    if (loA) {
        float inv = 1.f / ssum;
        float4 o0 = {a.x * inv, a.y * inv, a.z * inv, a.w * inv};
        float4 o1 = {b.x * inv, b.y * inv, b.z * inv, b.w * inv};
        float4* op = (float4*)(out + (size_t)node * FEAT + hl * 8);
        op[0] = o0; op[1] = o1;
    }
}

// ---- fallback aggregation (fp32 source), self-normalizing ----
__global__ __launch_bounds__(256) void agg32_kernel(
    const float* __restrict__ h, const int* __restrict__ offs,
    const int* __restrict__ esrc, const float* __restrict__ ew,
    float* __restrict__ out, int n_nodes) {
    int lane = threadIdx.x & 63;
    int node = blockIdx.x * 4 + (threadIdx.x >> 6);
    if (node >= n_nodes) return;
    int beg = offs[node], end = offs[node + 1];
    const float4* __restrict__ hv = (const float4*)h;
    float4 acc = {0, 0, 0, 0};
    if (beg == end) {
        acc = hv[(size_t)node * FEAT4 + lane];
    } else {
        float ssum = 0.f;
        for (int base = beg; base < end; base += 64) {
            int k = base + lane;
            int sj = 0; float wj = 0.f;
            if (k < end) { sj = esrc[k]; wj = ew[k]; }
            ssum += wj;
            int cnt = min(64, end - base);
            for (int j = 0; j < cnt; ++j) {
                int   srcn = __shfl(sj, j, 64);
                float al   = __shfl(wj, j, 64);
                float4 hv4 = hv[(size_t)srcn * FEAT4 + lane];
                acc.x += al * hv4.x; acc.y += al * hv4.y;
                acc.z += al * hv4.z; acc.w += al * hv4.w;
            }
        }
        #pragma unroll
        for (int off = 32; off; off >>= 1) ssum += __shfl_xor(ssum, off, 64);
        float inv = 1.f / ssum;
        acc.x *= inv; acc.y *= inv; acc.z *= inv; acc.w *= inv;
    }
    ((float4*)out)[(size_t)node * FEAT4 + lane] = acc;
}

extern "C" void kernel_launch(void* const* d_in, const int* in_sizes, int n_in,
                              void* d_out, int out_size, void* d_ws, size_t ws_size,
                              hipStream_t stream) {
    const float* h    = (const float*)d_in[0];
    const int*   src  = (const int*)d_in[1];
    const int*   dst  = (const int*)d_in[2];
    const float* watt = (const float*)d_in[3];
    float* out = (float*)d_out;

    const int nN = in_sizes[0] / FEAT;   // 50000
    const int nE = in_sizes[1];          // 800000

    char* w = (char*)d_ws;
    size_t off = 0;
    auto take = [&](size_t bytes) -> char* {
        char* p = w + off;
        off = (off + bytes + 255) & ~(size_t)255;
        return p;
    };
    float* ps       = (float*)take((size_t)nN * 4);
    float* pd       = (float*)take((size_t)nN * 4);
    int*   deg      = (int*)take((size_t)nN * 4);
    int*   offs     = (int*)take((size_t)(nN + 1) * 4);
    int*   offs_mut = (int*)take((size_t)nN * 4);
    int*   esrc     = (int*)take((size_t)nE * 4);
    float* ew       = (float*)take((size_t)nE * 4);
    int*   partial  = (int*)take(64 * 4);
    char*  hh       = take((size_t)nN * FEAT * 2);   // 25.6 MB fp16 copy
    int fp16ok = (off <= ws_size) ? 1 : 0;

    hipMemsetAsync(deg, 0, (size_t)nN * 4, stream);

    int nPB = (nN + 3) / 4;          // proj/agg blocks (4 nodes each)
    int nEB = (nE + 255) / 256;      // edge blocks
    int nbN = (nN + 1023) / 1024;    // 49 scan blocks (<=64 required)
    fused1_kernel<<<nPB + nEB, 256, 0, stream>>>(h, watt, dst, ps, pd,
                                                 (uint2*)hh, deg, nN, nE, nPB, fp16ok);
    scan1_kernel<<<nbN, 1024, 0, stream>>>(deg, offs, partial, nN);
    scan2_kernel<<<1, 64, 0, stream>>>(partial, nbN);
    scan3_kernel<<<nbN, 1024, 0, stream>>>(offs, offs_mut, partial, nN, nE);
    edge2_kernel <<<nEB, 256, 0, stream>>>(src, dst, ps, pd, offs_mut, esrc, ew, nE);
    if (fp16ok)
        agg16_kernel<<<nPB, 256, 0, stream>>>(h, (const uint4*)hh, offs, esrc, ew, out, nN);
    else
        agg32_kernel<<<nPB, 256, 0, stream>>>(h, offs, esrc, ew, out, nN);
}

// Round 6
// 250.602 us; speedup vs baseline: 1.5081x; 1.0512x over previous
//
#include <hip/hip_runtime.h>
#include <hip/hip_fp16.h>

// GAT layer: N=50000 nodes, S=2 slots, D=128, E=800000 edges.
// out[n] = (sum_e{dst=n} w_e * h[src_e]) / (sum w_e)  for deg>0, else h[n]
// w_e = exp(leaky_relu(ps[src]+pd[dst]))  (segment-max dropped: a~N(0,1),
// exp range [7e-3,250], fp32-safe — validated R3/R4/R5)
//
// R6: edge2 was transaction-bound (5 random L2 ops/edge, WRITE 83MB from
// partial-line writebacks). Now: w recomputed in agg (ps gather is L2-hot),
// ew array deleted, edge2 = atomic + ONE 4B scattered store. scan2 merged
// into scan3 (6 graph nodes).

#define SLOPE 0.98f
#define FEAT 256          // S*D floats per node
#define FEAT4 64          // float4 per node

// ---- fused: [blocks < nPB] proj + fp16 compress ; [rest] degree histogram ----
__global__ __launch_bounds__(256) void fused1_kernel(
    const float* __restrict__ h, const float* __restrict__ watt,
    const int* __restrict__ dst,
    float* __restrict__ ps, float* __restrict__ pd,
    uint2* __restrict__ hh, int* __restrict__ deg,
    int n_nodes, int ne, int n_proj_blocks, int do_fp16) {
    if ((int)blockIdx.x < n_proj_blocks) {
        int lane = threadIdx.x & 63;
        int node = blockIdx.x * 4 + (threadIdx.x >> 6);
        if (node >= n_nodes) return;                       // wave-uniform
        const float4* hv = (const float4*)h;
        float4 f = hv[(size_t)node * FEAT4 + lane];        // floats 4l..4l+3
        if (do_fp16) {
            __half2 lo = __floats2half2_rn(f.x, f.y);
            __half2 hi = __floats2half2_rn(f.z, f.w);
            uint2 pk;
            pk.x = *(unsigned*)&lo;
            pk.y = *(unsigned*)&hi;
            hh[(size_t)node * FEAT4 + lane] = pk;          // same linear layout
        }
        float p_s = 0.f, p_d = 0.f;
        if (lane < 32) {                                   // slot0 = floats 0..127
            float4 w1 = ((const float4*)watt)[lane];       // watt[4l..4l+3]
            float4 w2 = ((const float4*)watt)[32 + lane];  // watt[128+4l..]
            p_s = f.x * w1.x + f.y * w1.y + f.z * w1.z + f.w * w1.w;
            p_d = f.x * w2.x + f.y * w2.y + f.z * w2.z + f.w * w2.w;
        }
        #pragma unroll
        for (int off = 32; off; off >>= 1) {
            p_s += __shfl_xor(p_s, off, 64);
            p_d += __shfl_xor(p_d, off, 64);
        }
        if (lane == 0) { ps[node] = p_s; pd[node] = p_d; }
    } else {
        int e = ((int)blockIdx.x - n_proj_blocks) * 256 + threadIdx.x;
        if (e < ne) atomicAdd(&deg[dst[e]], 1);
    }
}

// ---- scan1: per-block exclusive scan of deg, emit block totals ----
__global__ __launch_bounds__(1024) void scan1_kernel(
    const int* __restrict__ deg, int* __restrict__ offs,
    int* __restrict__ partial, int n) {
    __shared__ int wsum[16];
    int i = blockIdx.x * 1024 + threadIdx.x;
    int v = (i < n) ? deg[i] : 0;
    int lane = threadIdx.x & 63, wid = threadIdx.x >> 6;
    int incl = v;
    #pragma unroll
    for (int off = 1; off < 64; off <<= 1) {
        int t = __shfl_up(incl, off, 64);
        if (lane >= off) incl += t;
    }
    if (lane == 63) wsum[wid] = incl;
    __syncthreads();
    if (threadIdx.x < 16) {
        int t = wsum[threadIdx.x];
        #pragma unroll
        for (int off = 1; off < 16; off <<= 1) {
            int u = __shfl_up(t, off, 64);
            if ((int)threadIdx.x >= off) t += u;
        }
        wsum[threadIdx.x] = t;
    }
    __syncthreads();
    int wbase = wid ? wsum[wid - 1] : 0;
    if (i < n) offs[i] = wbase + incl - v;        // exclusive within block
    if (threadIdx.x == 1023) partial[blockIdx.x] = wsum[15];
}

// ---- scan3 (scan2 merged): every block redundantly scans the <=64 partials ----
__global__ __launch_bounds__(1024) void scan3_kernel(
    int* __restrict__ offs, int* __restrict__ offs_mut,
    const int* __restrict__ partial, int n, int ne, int nb) {
    __shared__ int base_sh;
    if (threadIdx.x < 64) {
        int lane = threadIdx.x;
        int v = (lane < nb) ? partial[lane] : 0;
        int incl = v;
        #pragma unroll
        for (int off = 1; off < 64; off <<= 1) {
            int t = __shfl_up(incl, off, 64);
            if (lane >= off) incl += t;
        }
        if (lane == (int)blockIdx.x) base_sh = incl - v;   // exclusive base
    }
    __syncthreads();
    int base = base_sh;
    int i = blockIdx.x * 1024 + threadIdx.x;
    if (i < n) {
        int v = offs[i] + base;
        offs[i] = v;
        offs_mut[i] = v;
    }
    if (i == 0) offs[n] = ne;
}

// ---- edge placement: atomic bump + ONE scattered 4B store ----
__global__ __launch_bounds__(256) void edge2_kernel(
    const int* __restrict__ src, const int* __restrict__ dst,
    int* __restrict__ offs_mut, int* __restrict__ esrc, int ne) {
    int e = blockIdx.x * 256 + threadIdx.x;
    if (e >= ne) return;
    int sn = src[e];
    int p = atomicAdd(&offs_mut[dst[e]], 1);
    esrc[p] = sn;
}

__device__ inline void accum8(float4& a, float4& b, uint4 p, float w) {
    __half2 h0 = *(__half2*)&p.x, h1 = *(__half2*)&p.y;
    __half2 h2 = *(__half2*)&p.z, h3 = *(__half2*)&p.w;
    float2 f0 = __half22float2(h0), f1 = __half22float2(h1);
    float2 f2 = __half22float2(h2), f3 = __half22float2(h3);
    a.x += w * f0.x; a.y += w * f0.y; a.z += w * f1.x; a.w += w * f1.y;
    b.x += w * f2.x; b.y += w * f2.y; b.z += w * f3.x; b.w += w * f3.y;
}

// ---- aggregation (fp16 source): wave/node, 2 edges/iter, w recomputed here ----
__global__ __launch_bounds__(256) void agg16_kernel(
    const float* __restrict__ h, const uint4* __restrict__ hh,
    const int* __restrict__ offs, const int* __restrict__ esrc,
    const float* __restrict__ ps, const float* __restrict__ pd,
    float* __restrict__ out, int n_nodes) {
    int lane = threadIdx.x & 63;
    int node = blockIdx.x * 4 + (threadIdx.x >> 6);
    if (node >= n_nodes) return;
    int beg = offs[node], end = offs[node + 1];
    if (beg == end) {                                    // keep old features
        const float4* hv = (const float4*)h;
        ((float4*)out)[(size_t)node * FEAT4 + lane] = hv[(size_t)node * FEAT4 + lane];
        return;
    }
    float pdn = pd[node];                                // wave-uniform
    int  hl  = lane & 31;
    bool loA = lane < 32;
    float4 a = {0, 0, 0, 0}, b = {0, 0, 0, 0};           // floats 8*hl .. 8*hl+7
    float ssum = 0.f;
    for (int base = beg; base < end; base += 64) {
        int k = base + lane;
        int sj = 0; float wj = 0.f;
        if (k < end) {
            sj = esrc[k];                                // coalesced
            float v = ps[sj] + pdn;                      // L2-hot 4B gather
            v = (v >= 0.0f) ? v : SLOPE * v;
            wj = __expf(v);
        }
        ssum += wj;
        int cnt = min(64, end - base);
        int t = 0;
        for (; t + 4 <= cnt; t += 4) {                   // 4 edges, 2 loads/lane
            int   s0 = __shfl(sj, t, 64),     s1 = __shfl(sj, t + 1, 64);
            int   s2 = __shfl(sj, t + 2, 64), s3 = __shfl(sj, t + 3, 64);
            float w0 = __shfl(wj, t, 64),     w1 = __shfl(wj, t + 1, 64);
            float w2 = __shfl(wj, t + 2, 64), w3 = __shfl(wj, t + 3, 64);
            int   iA = loA ? s0 : s1,  iB = loA ? s2 : s3;
            float wA = loA ? w0 : w1,  wB = loA ? w2 : w3;
            uint4 pA = hh[(size_t)iA * 32 + hl];         // independent
            uint4 pB = hh[(size_t)iB * 32 + hl];         // gathers
            accum8(a, b, pA, wA);
            accum8(a, b, pB, wB);
        }
        for (; t < cnt; t += 2) {                        // 1-3 remaining edges
            int  s0 = __shfl(sj, t, 64);
            bool hasB = (t + 1) < cnt;
            int   s1 = hasB ? __shfl(sj, t + 1, 64) : s0;
            float w0 = __shfl(wj, t, 64);
            float w1 = hasB ? __shfl(wj, t + 1, 64) : 0.f;
            int   iA = loA ? s0 : s1;
            float wA = loA ? w0 : w1;
            uint4 pA = hh[(size_t)iA * 32 + hl];
            accum8(a, b, pA, wA);
        }
    }
    // combine the two half-wave partials (lane m <-> lane m+32 hold same floats)
    a.x += __shfl_xor(a.x, 32, 64); a.y += __shfl_xor(a.y, 32, 64);
    a.z += __shfl_xor(a.z, 32, 64); a.w += __shfl_xor(a.w, 32, 64);
    b.x += __shfl_xor(b.x, 32, 64); b.y += __shfl_xor(b.y, 32, 64);
    b.z += __shfl_xor(b.z, 32, 64); b.w += __shfl_xor(b.w, 32, 64);
    #pragma unroll
    for (int off = 32; off; off >>= 1) ssum += __shfl_xor(ssum, off, 64);
    if (loA) {
        float inv = 1.f / ssum;
        float4 o0 = {a.x * inv, a.y * inv, a.z * inv, a.w * inv};
        float4 o1 = {b.x * inv, b.y * inv, b.z * inv, b.w * inv};
        float4* op = (float4*)(out + (size_t)node * FEAT + hl * 8);
        op[0] = o0; op[1] = o1;
    }
}

// ---- fallback aggregation (fp32 source), w recomputed here ----
__global__ __launch_bounds__(256) void agg32_kernel(
    const float* __restrict__ h, const int* __restrict__ offs,
    const int* __restrict__ esrc,
    const float* __restrict__ ps, const float* __restrict__ pd,
    float* __restrict__ out, int n_nodes) {
    int lane = threadIdx.x & 63;
    int node = blockIdx.x * 4 + (threadIdx.x >> 6);
    if (node >= n_nodes) return;
    int beg = offs[node], end = offs[node + 1];
    const float4* __restrict__ hv = (const float4*)h;
    float4 acc = {0, 0, 0, 0};
    if (beg == end) {
        acc = hv[(size_t)node * FEAT4 + lane];
    } else {
        float pdn = pd[node];
        float ssum = 0.f;
        for (int base = beg; base < end; base += 64) {
            int k = base + lane;
            int sj = 0; float wj = 0.f;
            if (k < end) {
                sj = esrc[k];
                float v = ps[sj] + pdn;
                v = (v >= 0.0f) ? v : SLOPE * v;
                wj = __expf(v);
            }
            ssum += wj;
            int cnt = min(64, end - base);
            for (int j = 0; j < cnt; ++j) {
                int   srcn = __shfl(sj, j, 64);
                float al   = __shfl(wj, j, 64);
                float4 hv4 = hv[(size_t)srcn * FEAT4 + lane];
                acc.x += al * hv4.x; acc.y += al * hv4.y;
                acc.z += al * hv4.z; acc.w += al * hv4.w;
            }
        }
        #pragma unroll
        for (int off = 32; off; off >>= 1) ssum += __shfl_xor(ssum, off, 64);
        float inv = 1.f / ssum;
        acc.x *= inv; acc.y *= inv; acc.z *= inv; acc.w *= inv;
    }
    ((float4*)out)[(size_t)node * FEAT4 + lane] = acc;
}

extern "C" void kernel_launch(void* const* d_in, const int* in_sizes, int n_in,
                              void* d_out, int out_size, void* d_ws, size_t ws_size,
                              hipStream_t stream) {
    const float* h    = (const float*)d_in[0];
    const int*   src  = (const int*)d_in[1];
    const int*   dst  = (const int*)d_in[2];
    const float* watt = (const float*)d_in[3];
    float* out = (float*)d_out;

    const int nN = in_sizes[0] / FEAT;   // 50000
    const int nE = in_sizes[1];          // 800000

    char* w = (char*)d_ws;
    size_t off = 0;
    auto take = [&](size_t bytes) -> char* {
        char* p = w + off;
        off = (off + bytes + 255) & ~(size_t)255;
        return p;
    };
    float* ps       = (float*)take((size_t)nN * 4);
    float* pd       = (float*)take((size_t)nN * 4);
    int*   deg      = (int*)take((size_t)nN * 4);
    int*   offs     = (int*)take((size_t)(nN + 1) * 4);
    int*   offs_mut = (int*)take((size_t)nN * 4);
    int*   esrc     = (int*)take((size_t)nE * 4);
    int*   partial  = (int*)take(64 * 4);
    char*  hh       = take((size_t)nN * FEAT * 2);   // 25.6 MB fp16 copy
    int fp16ok = (off <= ws_size) ? 1 : 0;

    hipMemsetAsync(deg, 0, (size_t)nN * 4, stream);

    int nPB = (nN + 3) / 4;          // proj/agg blocks (4 nodes each)
    int nEB = (nE + 255) / 256;      // edge blocks
    int nbN = (nN + 1023) / 1024;    // 49 scan blocks (<=64 required)
    fused1_kernel<<<nPB + nEB, 256, 0, stream>>>(h, watt, dst, ps, pd,
                                                 (uint2*)hh, deg, nN, nE, nPB, fp16ok);
    scan1_kernel<<<nbN, 1024, 0, stream>>>(deg, offs, partial, nN);
    scan3_kernel<<<nbN, 1024, 0, stream>>>(offs, offs_mut, partial, nN, nE, nbN);
    edge2_kernel<<<nEB, 256, 0, stream>>>(src, dst, offs_mut, esrc, nE);
    if (fp16ok)
        agg16_kernel<<<nPB, 256, 0, stream>>>(h, (const uint4*)hh, offs, esrc, ps, pd, out, nN);
    else
        agg32_kernel<<<nPB, 256, 0, stream>>>(h, offs, esrc, ps, pd, out, nN);
}